// Round 4
// baseline (402.527 us; speedup 1.0000x reference)
//
#include <hip/hip_runtime.h>
#include <hip/hip_bf16.h>

#define DIM 1024

typedef int   i32x4 __attribute__((ext_vector_type(4)));
typedef float f32x4 __attribute__((ext_vector_type(4)));

__global__ __launch_bounds__(256) void emb_gather_kernel(
    const int* __restrict__ input_ids,   // (B*S)
    const int* __restrict__ base_idx,    // (V, D)
    const int* __restrict__ fine_idx,    // (V, D)
    const float* __restrict__ lut,       // (65536)
    float* __restrict__ out,             // (B*S, D)
    int n_tokens)
{
    const int token = blockIdx.x;
    if (token >= n_tokens) return;

    const int id = input_ids[token];                 // wave-uniform broadcast
    const int d0 = threadIdx.x << 2;                 // 256 threads * 4 = 1024
    const long long rowoff = (long long)id * DIM + d0;

    i32x4 b = *reinterpret_cast<const i32x4*>(base_idx + rowoff);
    i32x4 f = *reinterpret_cast<const i32x4*>(fine_idx + rowoff);

    f32x4 o;
    o.x = lut[(b.x << 8) + f.x];
    o.y = lut[(b.y << 8) + f.y];
    o.z = lut[(b.z << 8) + f.z];
    o.w = lut[(b.w << 8) + f.w];

    // Write-once output: nontemporal store keeps L2 for lut + index rows.
    __builtin_nontemporal_store(o, reinterpret_cast<f32x4*>(out + (long long)token * DIM + d0));
}

extern "C" void kernel_launch(void* const* d_in, const int* in_sizes, int n_in,
                              void* d_out, int out_size, void* d_ws, size_t ws_size,
                              hipStream_t stream)
{
    const int*   input_ids = (const int*)d_in[0];
    const int*   base_idx  = (const int*)d_in[1];
    const int*   fine_idx  = (const int*)d_in[2];
    const float* lut       = (const float*)d_in[3];
    float*       out       = (float*)d_out;

    const int n_tokens = in_sizes[0];                // B*S = 16384

    dim3 grid(n_tokens);
    dim3 block(256);
    emb_gather_kernel<<<grid, block, 0, stream>>>(
        input_ids, base_idx, fine_idx, lut, out, n_tokens);
}